// Round 2
// baseline (107.614 us; speedup 1.0000x reference)
//
#include <hip/hip_runtime.h>

// UCBNorm: x[B,T,D], mean[K,D], variance[K,D], prior[K,1] (softmax over size-1
// axis == 1.0, so prior only contributes the constant 1/sqrt(1+EPS)).
//
// Math (with p = exp(-0.5*(x-m)^2/(softplus(v)+EPS)), den = sum_k p + EPS,
// tau = p/den, S[k,d] = sum_{b,t} tau + EPS):
//   expectation[k,b,d] = (sum_t tau*x)/T / S
//   var_kb[k,b,d]      = (sum_t tau^3*x^2)/T / S^3
//   out[b,t,d] = sum_k tau * (x - expectation) * rsqrt(var_kb+EPS) / sqrt(1+EPS)
//
// Two passes over x recomputing tau (8 exps/elem each), reductions via
// device-scope float atomics into d_ws, tiny finalize kernel in between.

namespace {
constexpr int K = 8, B = 16, T = 512, D = 256;
constexpr float EPS = 1e-3f;
constexpr int TCH = 32;          // t-chunks per b
constexpr int TSUB = T / TCH;    // 16 t per block
}

__global__ __launch_bounds__(256) void ucb_pass1(
    const float* __restrict__ x, const float* __restrict__ mean,
    const float* __restrict__ variance,
    float* __restrict__ st, float* __restrict__ s1, float* __restrict__ s3)
{
  const int d = threadIdx.x;            // one d per lane, coalesced over t
  const int b = blockIdx.x / TCH;
  const int tc = blockIdx.x % TCH;

  float m[K], nh[K];
#pragma unroll
  for (int k = 0; k < K; ++k) {
    m[k] = mean[k*D + d];
    float sp = log1pf(__expf(variance[k*D + d]));   // softplus
    nh[k] = -0.5f / (sp + EPS);
  }

  float ast[K], as1[K], as3[K];
#pragma unroll
  for (int k = 0; k < K; ++k) { ast[k] = 0.f; as1[k] = 0.f; as3[k] = 0.f; }

  const float* xp = x + ((size_t)b*T + (size_t)tc*TSUB)*D + d;
  for (int t = 0; t < TSUB; ++t) {
    float xv = xp[(size_t)t*D];
    float p[K];
    float den = EPS;
#pragma unroll
    for (int k = 0; k < K; ++k) {
      float df = xv - m[k];
      p[k] = __expf(nh[k]*df*df);
      den += p[k];
    }
    float rden = __builtin_amdgcn_rcpf(den);
#pragma unroll
    for (int k = 0; k < K; ++k) {
      float tau = p[k]*rden;
      float tx = tau*xv;
      ast[k] += tau;
      as1[k] += tx;
      as3[k] += tau*tx*tx;   // tau^3 x^2
    }
  }

#pragma unroll
  for (int k = 0; k < K; ++k) {
    atomicAdd(&st[k*D + d], ast[k]);
    atomicAdd(&s1[(k*B + b)*D + d], as1[k]);
    atomicAdd(&s3[(k*B + b)*D + d], as3[k]);
  }
}

__global__ __launch_bounds__(256) void ucb_finalize(
    const float* __restrict__ st, const float* __restrict__ s1,
    const float* __restrict__ s3, float* __restrict__ ex, float* __restrict__ rs)
{
  int idx = blockIdx.x*256 + threadIdx.x;   // [K][B][D] flat = 32768
  int d = idx % D;
  int k = idx / (B*D);
  float S = st[k*D + d] + EPS;
  float rS = 1.0f / S;
  float e = s1[idx] * (1.0f/T) * rS;
  float var_kb = s3[idx] * (1.0f/T) * (rS*rS*rS);
  ex[idx] = e;
  rs[idx] = rsqrtf(var_kb + EPS);
}

__global__ __launch_bounds__(256) void ucb_pass2(
    const float* __restrict__ x, const float* __restrict__ mean,
    const float* __restrict__ variance, const float* __restrict__ ex,
    const float* __restrict__ rs, float* __restrict__ out)
{
  const int d = threadIdx.x;
  const int b = blockIdx.x / TCH;
  const int tc = blockIdx.x % TCH;

  float m[K], nh[K], e[K], r[K];
#pragma unroll
  for (int k = 0; k < K; ++k) {
    m[k] = mean[k*D + d];
    float sp = log1pf(__expf(variance[k*D + d]));
    nh[k] = -0.5f / (sp + EPS);
    e[k] = ex[(k*B + b)*D + d];
    r[k] = rs[(k*B + b)*D + d];
  }

  const float isp = 0.99950037f;  // 1/sqrt(1+EPS)
  const size_t base = ((size_t)b*T + (size_t)tc*TSUB)*D + d;
  for (int t = 0; t < TSUB; ++t) {
    float xv = x[base + (size_t)t*D];
    float p[K];
    float den = EPS;
#pragma unroll
    for (int k = 0; k < K; ++k) {
      float df = xv - m[k];
      p[k] = __expf(nh[k]*df*df);
      den += p[k];
    }
    float rden = __builtin_amdgcn_rcpf(den);
    float acc = 0.f;
#pragma unroll
    for (int k = 0; k < K; ++k) {
      float tau = p[k]*rden;
      acc += tau * (xv - e[k]) * r[k];
    }
    out[base + (size_t)t*D] = acc * isp;
  }
}

extern "C" void kernel_launch(void* const* d_in, const int* in_sizes, int n_in,
                              void* d_out, int out_size, void* d_ws, size_t ws_size,
                              hipStream_t stream) {
  const float* x        = (const float*)d_in[0];
  const float* mean     = (const float*)d_in[1];
  const float* variance = (const float*)d_in[2];
  // d_in[3] (prior) is mathematically unused: softmax over a size-1 axis == 1.

  float* out = (float*)d_out;
  float* w  = (float*)d_ws;
  float* st = w;                 // K*D
  float* s1 = st + K*D;          // K*B*D
  float* s3 = s1 + K*B*D;        // K*B*D
  float* ex = s3 + K*B*D;        // K*B*D
  float* rs = ex + K*B*D;        // K*B*D

  // zero the atomic accumulators (ws is poisoned with 0xAA before each call)
  hipMemsetAsync(st, 0, (size_t)(K*D + 2*K*B*D)*sizeof(float), stream);

  ucb_pass1<<<B*TCH, 256, 0, stream>>>(x, mean, variance, st, s1, s3);
  ucb_finalize<<<(K*B*D)/256, 256, 0, stream>>>(st, s1, s3, ex, rs);
  ucb_pass2<<<B*TCH, 256, 0, stream>>>(x, mean, variance, ex, rs, out);
}